// Round 5
// baseline (113.374 us; speedup 1.0000x reference)
//
#include <hip/hip_runtime.h>
#include <hip/hip_bf16.h>
#include <math.h>

typedef __attribute__((ext_vector_type(8))) short short8;
typedef __attribute__((ext_vector_type(4))) short s16x4;
typedef __attribute__((ext_vector_type(4))) float f32x4;

#define BB 4
#define HW 4096
#define CC 256
#define FC 64
#define L2E 1.4426950408889634f

// ws byte offsets
#define OFF_EMB   0                      // short[16384*64]   = 2 MB
#define OFF_SCT2  (2*1024*1024)          // short[4*64*8*256*8] = 8 MB
#define OFF_SQN   (OFF_SCT2 + 8*1024*1024)
#define OFF_T     (OFF_SQN + 65536)
#define OFF_D     (OFF_T   + 65536)
#define OFF_WEMB2 (OFF_D   + 65536)      // short[32*64*8] = 32 KB
#define OFF_WATT2 (OFF_WEMB2 + 32768)    // short[32*256*8] = 128 KB

static __device__ __forceinline__ short f2bf(float f) {
    __hip_bfloat16 h = __float2bfloat16(f);
    return *reinterpret_cast<short*>(&h);
}
static __device__ __forceinline__ float bf2f(short s) {
    __hip_bfloat16 h = *reinterpret_cast<__hip_bfloat16*>(&s);
    return __bfloat162float(h);
}
static __device__ __forceinline__ float fexp2(float x) {
#if __has_builtin(__builtin_amdgcn_exp2f)
    return __builtin_amdgcn_exp2f(x);
#else
    float r; asm("v_exp_f32 %0, %1" : "=v"(r) : "v"(x)); return r;
#endif
}
static __device__ __forceinline__ float frcp(float x) {
#if __has_builtin(__builtin_amdgcn_rcpf)
    return __builtin_amdgcn_rcpf(x);
#else
    return 1.0f / x;
#endif
}
// transform: sim=exp(-relu(d2)), A=relu(sim-T), P=exp(A)/D  (exp2-folded)
static __device__ __forceinline__ short xf1(float dot, float sq, float tt,
                                            float id, float sni) {
    float x1 = fminf(fmaf(dot, 2.f*L2E, fmaf(-L2E, sq, sni)), 0.f);
    float e1 = fexp2(x1);
    float a_ = fmaxf(fmaf(e1, L2E, -L2E*tt), 0.f);
    return f2bf(fexp2(a_) * id);
}

// ---------------------------------------------------------------------------
// K0: weight conversion to tiled bf16 B-fragment layouts + D zero.
// ---------------------------------------------------------------------------
__global__ __launch_bounds__(256) void k_prep(const float* __restrict__ Wemb,
    const float* __restrict__ Watt, short* __restrict__ Wemb2,
    short* __restrict__ Watt2, float* __restrict__ D)
{
    const int bid = blockIdx.x, t = threadIdx.x;
    if (bid < 256) {
        Watt2[(size_t)(t>>3)*2048 + bid*8 + (t&7)] = f2bf(Watt[(size_t)bid*256 + t]);
        if (bid < 64) D[bid*256 + t] = 0.f;
    } else {
        const int f = bid - 256;
        Wemb2[(size_t)(t>>3)*512 + f*8 + (t&7)] = f2bf(Wemb[(size_t)f*256 + t]);
    }
}

// ---------------------------------------------------------------------------
// K1 (fused emb + shortcut + threshold, all MFMA). grid 1024 x 256.
// ---------------------------------------------------------------------------
__global__ __launch_bounds__(256) void k_front(const float* __restrict__ fm,
    const short* __restrict__ Wemb2, const short* __restrict__ Watt2,
    const float* __restrict__ bemb, const float* __restrict__ batt,
    const float* __restrict__ wthr, const float* __restrict__ bthr,
    short* __restrict__ emb, short* __restrict__ sct2,
    float* __restrict__ sqn, float* __restrict__ T)
{
    const int blk = blockIdx.x;
    const int b = blk >> 8;
    const int r0 = (blk & 255) * 16;
    const int t = threadIdx.x;
    const int w = t >> 6, lane = t & 63, g = lane >> 4, n16 = lane & 15;
    __shared__ short fmt[16*256];
    __shared__ float tred[16][4];
    __shared__ float qred[16][4];
    #pragma unroll
    for (int v = t; v < 512; v += 256) {
        const int row = v >> 5, c32 = v & 31;
        const float4* src = (const float4*)(fm + ((size_t)b*HW + r0 + row)*CC + c32*8);
        float4 x0 = src[0], x1 = src[1];
        short8 pv;
        pv[0]=f2bf(x0.x); pv[1]=f2bf(x0.y); pv[2]=f2bf(x0.z); pv[3]=f2bf(x0.w);
        pv[4]=f2bf(x1.x); pv[5]=f2bf(x1.y); pv[6]=f2bf(x1.z); pv[7]=f2bf(x1.w);
        *(short8*)((char*)fmt + row*512 + ((c32*16) ^ ((row&7)<<4))) = pv;
    }
    __syncthreads();
    const int cb = w*64, fb = w*16;
    f32x4 acc[4], acce;
    #pragma unroll
    for (int nn = 0; nn < 4; ++nn) acc[nn] = (f32x4){0.f,0.f,0.f,0.f};
    acce = (f32x4){0.f,0.f,0.f,0.f};
    #pragma unroll
    for (int kk = 0; kk < 8; ++kk) {
        const int kc = kk*4 + g;
        short8 a = *(const short8*)((const char*)fmt + n16*512 + ((kc*16) ^ ((n16&7)<<4)));
        const short* wb = Watt2 + (size_t)kc*2048 + (cb + n16)*8;
        #pragma unroll
        for (int nn = 0; nn < 4; ++nn) {
            short8 bv = *(const short8*)(wb + nn*128);
            acc[nn] = __builtin_amdgcn_mfma_f32_16x16x32_bf16(a, bv, acc[nn], 0, 0, 0);
        }
        short8 be = *(const short8*)(Wemb2 + (size_t)kc*512 + (fb + n16)*8);
        acce = __builtin_amdgcn_mfma_f32_16x16x32_bf16(a, be, acce, 0, 0, 0);
    }
    float tp[4] = {0.f,0.f,0.f,0.f};
    const int jt_ = r0 >> 6;
    const int jc0 = (r0 & 63) >> 3;
    const size_t tilebase = ((size_t)b*64 + jt_)*8;
    #pragma unroll
    for (int nn = 0; nn < 4; ++nn) {
        const int ch = cb + nn*16 + n16;
        const float ba_ = batt[ch], wt_ = wthr[ch];
        float v[4];
        #pragma unroll
        for (int r = 0; r < 4; ++r) { v[r] = acc[nn][r] + ba_; tp[r] = fmaf(v[r], wt_, tp[r]); }
        const int jc = jc0 + (g >> 1);
        const int jw0 = (g & 1)*4;
        short* dstp = sct2 + (tilebase + jc)*2048 + (size_t)ch*8;
        unsigned u01 = (unsigned short)f2bf(v[0]) | ((unsigned)(unsigned short)f2bf(v[1]) << 16);
        unsigned u23 = (unsigned short)f2bf(v[2]) | ((unsigned)(unsigned short)f2bf(v[3]) << 16);
        *(unsigned*)(dstp + jw0)     = u01;
        *(unsigned*)(dstp + jw0 + 2) = u23;
    }
    #pragma unroll
    for (int r = 0; r < 4; ++r)
        #pragma unroll
        for (int off = 1; off <= 8; off <<= 1) tp[r] += __shfl_xor(tp[r], off);
    const int f = fb + n16;
    const float be_ = bemb[f];
    float qp[4];
    #pragma unroll
    for (int r = 0; r < 4; ++r) {
        short bv = f2bf(acce[r] + be_);
        emb[((size_t)b*HW + r0 + g*4 + r)*FC + f] = bv;
        float ef = bf2f(bv);
        qp[r] = ef*ef;
        #pragma unroll
        for (int off = 1; off <= 8; off <<= 1) qp[r] += __shfl_xor(qp[r], off);
    }
    if (n16 == 0) {
        #pragma unroll
        for (int r = 0; r < 4; ++r) { tred[g*4+r][w] = tp[r]; qred[g*4+r][w] = qp[r]; }
    }
    __syncthreads();
    if (t < 16) {
        T[(size_t)b*HW + r0 + t]   = tred[t][0]+tred[t][1]+tred[t][2]+tred[t][3] + bthr[0];
        sqn[(size_t)b*HW + r0 + t] = qred[t][0]+qred[t][1]+qred[t][2]+qred[t][3];
    }
}

// ---------------------------------------------------------------------------
// K2: column sums D[j]. grid 2048 x 256. 1 barrier/iter, dbuf ei.
// ---------------------------------------------------------------------------
__global__ __launch_bounds__(256) void k_colsum(const short* __restrict__ emb,
    const float* __restrict__ sqn, const float* __restrict__ T,
    float* __restrict__ D)
{
    const int bid = blockIdx.x;
    const int split = bid & 7, jt = (bid >> 3) & 63, b = bid >> 9;
    const int t = threadIdx.x, w = t >> 6, lane = t & 63, g = lane >> 4, n16 = lane & 15;
    const size_t jbase = (size_t)b*HW + jt*64;
    __shared__ short ej[64*64];
    __shared__ short ei[2][64*64];
    __shared__ float sqni[2][64];
    #pragma unroll
    for (int v = t; v < 512; v += 256) {
        const int row = v >> 3, c8 = v & 7;
        short8 x = *(const short8*)(emb + (jbase + row)*FC + c8*8);
        *(short8*)((char*)ej + row*128 + ((c8*16) ^ ((row&7)<<4))) = x;
    }
    const int jl = w*16 + n16;
    const float sqjL = -L2E * sqn[jbase + jl];
    const float tjL  = -L2E * T[jbase + jl];
    const int srow0 = t >> 3, srow1 = (t >> 3) + 32, sc8 = t & 7;
    const int sb0 = srow0*128 + ((sc8*16) ^ ((srow0&7)<<4));
    const int sb1 = srow1*128 + ((sc8*16) ^ ((srow1&7)<<4));
    const size_t base0 = (size_t)b*HW + (size_t)split*512;
    short8 stg0 = *(const short8*)(emb + (base0 + srow0)*FC + sc8*8);
    short8 stg1 = *(const short8*)(emb + (base0 + srow1)*FC + sc8*8);
    float stgq = (t < 64) ? sqn[base0 + t] : 0.f;
    *(short8*)((char*)ei[0] + sb0) = stg0;
    *(short8*)((char*)ei[0] + sb1) = stg1;
    if (t < 64) sqni[0][t] = stgq;
    stg0 = *(const short8*)(emb + (base0 + 64 + srow0)*FC + sc8*8);
    stg1 = *(const short8*)(emb + (base0 + 64 + srow1)*FC + sc8*8);
    stgq = (t < 64) ? sqn[base0 + 64 + t] : 0.f;
    __syncthreads();
    const short8 bf0 = *(const short8*)((const char*)ej + jl*128 + ((g*16)     ^ ((jl&7)<<4)));
    const short8 bf1 = *(const short8*)((const char*)ej + jl*128 + (((g+4)*16) ^ ((jl&7)<<4)));
    float csum = 0.f;
    for (int it = 0; it < 8; ++it) {
        if (it < 7) {
            char* eib = (char*)ei[(it+1)&1];
            *(short8*)(eib + sb0) = stg0;
            *(short8*)(eib + sb1) = stg1;
            if (t < 64) sqni[(it+1)&1][t] = stgq;
            if (it < 6) {
                const size_t nb = base0 + (size_t)(it+2)*64;
                stg0 = *(const short8*)(emb + (nb + srow0)*FC + sc8*8);
                stg1 = *(const short8*)(emb + (nb + srow1)*FC + sc8*8);
                stgq = (t < 64) ? sqn[nb + t] : 0.f;
            }
        }
        const char* eib = (const char*)ei[it&1];
        const float* sqc = sqni[it&1];
        #pragma unroll
        for (int m = 0; m < 4; ++m) {
            const int arow = m*16 + n16;
            short8 a0 = *(const short8*)(eib + arow*128 + ((g*16)     ^ ((arow&7)<<4)));
            short8 a1 = *(const short8*)(eib + arow*128 + (((g+4)*16) ^ ((arow&7)<<4)));
            f32x4 dot = {0.f,0.f,0.f,0.f};
            dot = __builtin_amdgcn_mfma_f32_16x16x32_bf16(a0, bf0, dot, 0, 0, 0);
            dot = __builtin_amdgcn_mfma_f32_16x16x32_bf16(a1, bf1, dot, 0, 0, 0);
            #pragma unroll
            for (int r = 0; r < 4; ++r) {
                float x1 = fminf(fmaf(dot[r], 2.f*L2E, fmaf(-L2E, sqc[m*16 + g*4 + r], sqjL)), 0.f);
                float e1 = fexp2(x1);
                float a_ = fmaxf(fmaf(e1, L2E, tjL), 0.f);
                csum += fexp2(a_);
            }
        }
        __syncthreads();
    }
    csum += __shfl_xor(csum, 16);
    csum += __shfl_xor(csum, 32);
    if (lane < 16) atomicAdd(&D[jbase + jl], csum);
}

// ---------------------------------------------------------------------------
// K3: fused score + normalize + PV, window-pipelined:
// each barrier window = score(K+1) + transform(K+1)  ||  PV(K)  (VALU || MFMA)
// Swapped score operands -> P writes are b64, scalars are float4 quads.
// grid 256 x 512. 64 rows/block.
// ---------------------------------------------------------------------------
#define PV2(PRr, BF, M0)                                                       \
  { _Pragma("unroll")                                                          \
    for (int m = M0; m < M0+2; ++m) {                                          \
      const int prow = m*16 + n16;                                             \
      short8 pa0 = *(const short8*)((PRr) + prow*128 + (((g)   ^ (prow&7))<<4)); \
      short8 pa1 = *(const short8*)((PRr) + prow*128 + (((4+g) ^ (prow&7))<<4)); \
      acc[m][0] = __builtin_amdgcn_mfma_f32_16x16x32_bf16(pa0, BF[0], acc[m][0], 0,0,0); \
      acc[m][0] = __builtin_amdgcn_mfma_f32_16x16x32_bf16(pa1, BF[1], acc[m][0], 0,0,0); \
      acc[m][1] = __builtin_amdgcn_mfma_f32_16x16x32_bf16(pa0, BF[2], acc[m][1], 0,0,0); \
      acc[m][1] = __builtin_amdgcn_mfma_f32_16x16x32_bf16(pa1, BF[3], acc[m][1], 0,0,0); } }

#define WINDOW(K, BFC, BFN, SQC, TC, DC, SQN_, TN_, DN_)                       \
  {                                                                            \
    const int kq2 = (K)+2 < 63 ? (K)+2 : 63;                                   \
    { const size_t jb = bbase + (size_t)kq2*64 + jq*16 + g*4;                  \
      SQN_ = *(const float4*)(sqn + jb); TN_ = *(const float4*)(T + jb);       \
      DN_ = *(const float4*)(D + jb); }                                        \
    { const int kb = (K)+1 < 63 ? (K)+1 : 63;                                  \
      const short* sbn = sct2 + ((size_t)(b*64 + kb)*8)*2048 + (size_t)(w*32 + n16)*8; \
      _Pragma("unroll")                                                        \
      for (int nn = 0; nn < 2; ++nn)                                           \
        _Pragma("unroll")                                                      \
        for (int kc = 0; kc < 2; ++kc)                                         \
          BFN[nn*2+kc] = *(const short8*)(sbn + (size_t)(kc*4+g)*2048 + nn*128); } \
    const char* ejb = (const char*)ejlds[((K)+1)&1];                           \
    char* Pw = (char*)Plds[((K)+1)&1];                                         \
    const char* Pr = (const char*)Plds[(K)&1];                                 \
    short8 aj0 = *(const short8*)(ejb + jl*128 + ((g*16) ^ ((jl&7)<<4)));      \
    short8 aj1 = *(const short8*)(ejb + jl*128 + (((g+4)*16) ^ ((jl&7)<<4)));  \
    f32x4 dot0 = {0.f,0.f,0.f,0.f}, dot1 = {0.f,0.f,0.f,0.f};                  \
    dot0 = __builtin_amdgcn_mfma_f32_16x16x32_bf16(aj0, aQ00, dot0, 0,0,0);    \
    dot0 = __builtin_amdgcn_mfma_f32_16x16x32_bf16(aj1, aQ10, dot0, 0,0,0);    \
    dot1 = __builtin_amdgcn_mfma_f32_16x16x32_bf16(aj0, aQ01, dot1, 0,0,0);    \
    dot1 = __builtin_amdgcn_mfma_f32_16x16x32_bf16(aj1, aQ11, dot1, 0,0,0);    \
    if ((K) < 62) {                                                            \
      *(short8*)((char*)ejlds[(K)&1] + sbyte) = stg;                           \
      const int k3 = (K)+3 < 63 ? (K)+3 : 63;                                  \
      stg = *(const short8*)(emb + (bbase + (size_t)k3*64 + srow)*FC + sc8*8); } \
    float4 idq; idq.x = frcp(DC.x); idq.y = frcp(DC.y);                        \
    idq.z = frcp(DC.z); idq.w = frcp(DC.w);                                    \
    { s16x4 pk;                                                                \
      pk[0] = xf1(dot0[0], SQC.x, TC.x, idq.x, sni0);                          \
      pk[1] = xf1(dot0[1], SQC.y, TC.y, idq.y, sni0);                          \
      pk[2] = xf1(dot0[2], SQC.z, TC.z, idq.z, sni0);                          \
      pk[3] = xf1(dot0[3], SQC.w, TC.w, idq.w, sni0);                          \
      const int prow = ihb + n16;                                              \
      *(s16x4*)(Pw + prow*128 + ((pgr ^ (prow&7))<<4) + pofs) = pk; }          \
    __builtin_amdgcn_s_setprio(1);                                             \
    PV2(Pr, BFC, 0);                                                           \
    __builtin_amdgcn_s_setprio(0);                                             \
    { s16x4 pk;                                                                \
      pk[0] = xf1(dot1[0], SQC.x, TC.x, idq.x, sni1);                          \
      pk[1] = xf1(dot1[1], SQC.y, TC.y, idq.y, sni1);                          \
      pk[2] = xf1(dot1[2], SQC.z, TC.z, idq.z, sni1);                          \
      pk[3] = xf1(dot1[3], SQC.w, TC.w, idq.w, sni1);                          \
      const int prow = ihb + 16 + n16;                                         \
      *(s16x4*)(Pw + prow*128 + ((pgr ^ (prow&7))<<4) + pofs) = pk; }          \
    __builtin_amdgcn_s_setprio(1);                                             \
    PV2(Pr, BFC, 2);                                                           \
    __builtin_amdgcn_s_setprio(0);                                             \
    __syncthreads();                                                           \
  }

__global__ __launch_bounds__(512) void k_attn(const float* __restrict__ fm,
    const short* __restrict__ emb, const float* __restrict__ sqn,
    const float* __restrict__ T, const float* __restrict__ D,
    const short* __restrict__ sct2, float* __restrict__ out)
{
    const int bid = ((blockIdx.x & 7) << 5) | (blockIdx.x >> 3);  // 256 blocks
    const int b = bid >> 6;
    const int i0 = (bid & 63) * 64;
    const int t = threadIdx.x, w = t >> 6, lane = t & 63, g = lane >> 4, n16 = lane & 15;
    const size_t bbase = (size_t)b * HW;
    const size_t ibase = bbase + i0;
    __shared__ short ejlds[2][64*64];
    __shared__ short Plds[2][64*64];

    const int ih = w & 1, jq = w >> 1;
    const int ihb = ih * 32;
    const int jl = jq*16 + n16;
    const int pgr = jq*2 + (g>>1), pofs = (g&1)*8;

    // ei fragments (MFMA B-operand) + per-lane i row norms
    const short8 aQ00 = *(const short8*)(emb + (ibase + ihb      + n16)*FC + g*8);
    const short8 aQ10 = *(const short8*)(emb + (ibase + ihb      + n16)*FC + g*8 + 32);
    const short8 aQ01 = *(const short8*)(emb + (ibase + ihb + 16 + n16)*FC + g*8);
    const short8 aQ11 = *(const short8*)(emb + (ibase + ihb + 16 + n16)*FC + g*8 + 32);
    const float sni0 = -L2E * sqn[ibase + ihb + n16];
    const float sni1 = -L2E * sqn[ibase + ihb + 16 + n16];

    const int srow = t >> 3, sc8 = t & 7;
    const int sbyte = srow*128 + ((sc8*16) ^ ((srow&7)<<4));
    short8 e0 = *(const short8*)(emb + (bbase + srow)*FC + sc8*8);
    *(short8*)((char*)ejlds[0] + sbyte) = e0;
    short8 stg = *(const short8*)(emb + (bbase + 64 + srow)*FC + sc8*8);

    // prologue scalar quads: tile0 (consumed now) + tile1 (window 0)
    const size_t jb0 = bbase + jq*16 + g*4;
    const float4 SQ0 = *(const float4*)(sqn + jb0);
    const float4 T0q = *(const float4*)(T + jb0);
    const float4 D0q = *(const float4*)(D + jb0);
    float4 SQA, TA, DA, SQB, TB, DB;
    { const size_t jb = bbase + 64 + jq*16 + g*4;
      SQA = *(const float4*)(sqn + jb); TA = *(const float4*)(T + jb);
      DA = *(const float4*)(D + jb); }
    short8 BFA[4], BFB[4];
    { const short* sb0 = sct2 + ((size_t)(b*64)*8)*2048 + (size_t)(w*32 + n16)*8;
      #pragma unroll
      for (int nn = 0; nn < 2; ++nn)
          #pragma unroll
          for (int kc = 0; kc < 2; ++kc)
              BFA[nn*2+kc] = *(const short8*)(sb0 + (size_t)(kc*4+g)*2048 + nn*128); }

    f32x4 acc[4][2];
    #pragma unroll
    for (int m = 0; m < 4; ++m) { acc[m][0] = (f32x4){0.f,0.f,0.f,0.f}; acc[m][1] = (f32x4){0.f,0.f,0.f,0.f}; }
    __syncthreads();            // ej[0] visible

    // prologue window: score tile 0 + transform -> P[0]; stage ej[1]
    {
        const char* ejb = (const char*)ejlds[0];
        char* Pw = (char*)Plds[0];
        short8 aj0 = *(const short8*)(ejb + jl*128 + ((g*16) ^ ((jl&7)<<4)));
        short8 aj1 = *(const short8*)(ejb + jl*128 + (((g+4)*16) ^ ((jl&7)<<4)));
        f32x4 dot0 = {0.f,0.f,0.f,0.f}, dot1 = {0.f,0.f,0.f,0.f};
        dot0 = __builtin_amdgcn_mfma_f32_16x16x32_bf16(aj0, aQ00, dot0, 0,0,0);
        dot0 = __builtin_amdgcn_mfma_f32_16x16x32_bf16(aj1, aQ10, dot0, 0,0,0);
        dot1 = __builtin_amdgcn_mfma_f32_16x16x32_bf16(aj0, aQ01, dot1, 0,0,0);
        dot1 = __builtin_amdgcn_mfma_f32_16x16x32_bf16(aj1, aQ11, dot1, 0,0,0);
        *(short8*)((char*)ejlds[1] + sbyte) = stg;
        stg = *(const short8*)(emb + (bbase + 128 + srow)*FC + sc8*8);
        float4 idq; idq.x = frcp(D0q.x); idq.y = frcp(D0q.y);
        idq.z = frcp(D0q.z); idq.w = frcp(D0q.w);
        { s16x4 pk;
          pk[0] = xf1(dot0[0], SQ0.x, T0q.x, idq.x, sni0);
          pk[1] = xf1(dot0[1], SQ0.y, T0q.y, idq.y, sni0);
          pk[2] = xf1(dot0[2], SQ0.z, T0q.z, idq.z, sni0);
          pk[3] = xf1(dot0[3], SQ0.w, T0q.w, idq.w, sni0);
          const int prow = ihb + n16;
          *(s16x4*)(Pw + prow*128 + ((pgr ^ (prow&7))<<4) + pofs) = pk; }
        { s16x4 pk;
          pk[0] = xf1(dot1[0], SQ0.x, T0q.x, idq.x, sni1);
          pk[1] = xf1(dot1[1], SQ0.y, T0q.y, idq.y, sni1);
          pk[2] = xf1(dot1[2], SQ0.z, T0q.z, idq.z, sni1);
          pk[3] = xf1(dot1[3], SQ0.w, T0q.w, idq.w, sni1);
          const int prow = ihb + 16 + n16;
          *(s16x4*)(Pw + prow*128 + ((pgr ^ (prow&7))<<4) + pofs) = pk; }
        __syncthreads();        // P[0], ej[1] visible
    }

    for (int k2 = 0; k2 < 62; k2 += 2) {
        WINDOW(k2,   BFA, BFB, SQA, TA, DA, SQB, TB, DB);
        WINDOW(k2+1, BFB, BFA, SQB, TB, DB, SQA, TA, DA);
    }
    WINDOW(62, BFA, BFB, SQA, TA, DA, SQB, TB, DB);

    // epilogue: PV tile 63 (P[1], BFB)
    {
        const char* Pr = (const char*)Plds[1];
        __builtin_amdgcn_s_setprio(1);
        PV2(Pr, BFB, 0);
        PV2(Pr, BFB, 2);
        __builtin_amdgcn_s_setprio(0);
    }

    #pragma unroll
    for (int m = 0; m < 4; ++m)
        #pragma unroll
        for (int r = 0; r < 4; ++r) {
            const size_t row = ibase + m*16 + g*4 + r;
            #pragma unroll
            for (int nn = 0; nn < 2; ++nn) {
                const size_t idx = row*CC + w*32 + nn*16 + n16;
                out[idx] = fm[idx] + acc[m][nn][r];
            }
        }
}

extern "C" void kernel_launch(void* const* d_in, const int* in_sizes, int n_in,
                              void* d_out, int out_size, void* d_ws, size_t ws_size,
                              hipStream_t stream)
{
    const float* fm   = (const float*)d_in[0];
    const float* Wemb = (const float*)d_in[1];
    const float* bemb = (const float*)d_in[2];
    const float* Watt = (const float*)d_in[3];
    const float* batt = (const float*)d_in[4];
    const float* Wthr = (const float*)d_in[5];
    const float* bthr = (const float*)d_in[6];
    char* ws = (char*)d_ws;
    short* emb   = (short*)(ws + OFF_EMB);
    short* sct2  = (short*)(ws + OFF_SCT2);
    float* sqn   = (float*)(ws + OFF_SQN);
    float* T     = (float*)(ws + OFF_T);
    float* D     = (float*)(ws + OFF_D);
    short* Wemb2 = (short*)(ws + OFF_WEMB2);
    short* Watt2 = (short*)(ws + OFF_WATT2);
    float* out = (float*)d_out;

    k_prep  <<<320,  256, 0, stream>>>(Wemb, Watt, Wemb2, Watt2, D);
    k_front <<<1024, 256, 0, stream>>>(fm, Wemb2, Watt2, bemb, batt, Wthr, bthr,
                                       emb, sct2, sqn, T);
    k_colsum<<<2048, 256, 0, stream>>>(emb, sqn, T, D);
    k_attn  <<<256,  512, 0, stream>>>(fm, emb, sqn, T, D, sct2, out);
}